// Round 1
// baseline (591.891 us; speedup 1.0000x reference)
//
#include <hip/hip_runtime.h>

// Problem dims (fixed by reference)
#define BB   2
#define NBB  32
#define PP   128
#define FF   32
#define HH   32
#define NO   8
#define OUTC 32
#define NROWS (BB*NBB*PP)   // 8192
#define ICHUNK 4

__device__ __forceinline__ float elu_f(float x){
    return x > 0.0f ? x : (__expf(x) - 1.0f);
}

// Kernel A: node MLP + projection to pa/pb. One thread per row.
// pa gets pair_b0 folded in so kernel B's h0 = elu(pa_i + pb_j).
__global__ __launch_bounds__(256) void node_kernel(
    const float* __restrict__ x,  const float* __restrict__ msk,
    const float* __restrict__ w0, const float* __restrict__ b0,
    const float* __restrict__ w1, const float* __restrict__ b1,
    const float* __restrict__ w2, const float* __restrict__ b2,
    const float* __restrict__ pw0,const float* __restrict__ pb0,
    float* __restrict__ pa, float* __restrict__ pb)
{
    int row = blockIdx.x*256 + threadIdx.x;
    if (row >= NROWS) return;

    float xr[FF];
    const float4* xp = reinterpret_cast<const float4*>(x + (size_t)row*FF);
#pragma unroll
    for (int q=0;q<FF/4;q++){ float4 v=xp[q]; xr[4*q]=v.x; xr[4*q+1]=v.y; xr[4*q+2]=v.z; xr[4*q+3]=v.w; }

    float h[HH];
#pragma unroll
    for (int k=0;k<HH;k++) h[k]=b0[k];
#pragma unroll
    for (int m=0;m<FF;m++){
        float xm = xr[m];
#pragma unroll
        for (int k=0;k<HH;k++) h[k] += xm * w0[m*HH+k];
    }
#pragma unroll
    for (int k=0;k<HH;k++) h[k]=elu_f(h[k]);

    float g[HH];
#pragma unroll
    for (int k=0;k<HH;k++) g[k]=b1[k];
#pragma unroll
    for (int m=0;m<HH;m++){
        float hm=h[m];
#pragma unroll
        for (int k=0;k<HH;k++) g[k] += hm * w1[m*HH+k];
    }
#pragma unroll
    for (int k=0;k<HH;k++) g[k]=elu_f(g[k]);

    float mk = msk[row];
    float npj[NO];
#pragma unroll
    for (int k=0;k<NO;k++) npj[k]=b2[k];
#pragma unroll
    for (int m=0;m<HH;m++){
        float gm=g[m];
#pragma unroll
        for (int k=0;k<NO;k++) npj[k] += gm * w2[m*NO+k];
    }
#pragma unroll
    for (int k=0;k<NO;k++) npj[k]=elu_f(npj[k])*mk;

    float pav[HH], pbv[HH];
#pragma unroll
    for (int k=0;k<HH;k++){ pav[k]=pb0[k]; pbv[k]=0.0f; }
#pragma unroll
    for (int m=0;m<NO;m++){
        float nm=npj[m];
#pragma unroll
        for (int k=0;k<HH;k++){
            pav[k] += nm * pw0[m*HH+k];
            pbv[k] += nm * pw0[(NO+m)*HH+k];
        }
    }
    float4* pap = reinterpret_cast<float4*>(pa + (size_t)row*HH);
    float4* pbp = reinterpret_cast<float4*>(pb + (size_t)row*HH);
#pragma unroll
    for (int q=0;q<HH/4;q++){
        pap[q]=make_float4(pav[4*q],pav[4*q+1],pav[4*q+2],pav[4*q+3]);
        pbp[q]=make_float4(pbv[4*q],pbv[4*q+1],pbv[4*q+2],pbv[4*q+3]);
    }
}

// Kernel B: one thread = one (i,j) pair, full 32->32->32 MLP in registers.
// Weights are wave-uniform with compile-time offsets -> scalar (SGPR) loads;
// each v_fmac takes the weight as the single allowed SGPR operand.
__global__ __launch_bounds__(128) void pair_kernel(
    const float* __restrict__ pa, const float* __restrict__ pb,
    const float* __restrict__ w1, const float* __restrict__ b1,
    const float* __restrict__ w2, const float* __restrict__ b2,
    float* __restrict__ out)
{
    const int bnb = blockIdx.x / (PP/ICHUNK);
    const int i0  = (blockIdx.x % (PP/ICHUNK)) * ICHUNK;
    const int j   = threadIdx.x;           // 0..127 -> pb row

    float vb[HH];
    const float4* pbp = reinterpret_cast<const float4*>(pb + ((size_t)bnb*PP + j)*HH);
#pragma unroll
    for (int q=0;q<HH/4;q++){ float4 v=pbp[q]; vb[4*q]=v.x; vb[4*q+1]=v.y; vb[4*q+2]=v.z; vb[4*q+3]=v.w; }

    for (int ii=0; ii<ICHUNK; ii++){
        const int i = i0+ii;
        const float* par = pa + ((size_t)bnb*PP + i)*HH;   // uniform -> s_load

        float h0[HH];
#pragma unroll
        for (int m=0;m<HH;m++) h0[m] = elu_f(par[m] + vb[m]);

        float h1[HH];
#pragma unroll
        for (int k=0;k<HH;k++) h1[k]=b1[k];
#pragma unroll
        for (int m=0;m<HH;m++){
            float hm=h0[m];
#pragma unroll
            for (int k=0;k<HH;k++) h1[k] += hm * w1[m*HH+k];
        }
#pragma unroll
        for (int k=0;k<HH;k++) h1[k]=elu_f(h1[k]);

        float o[OUTC];
#pragma unroll
        for (int k=0;k<OUTC;k++) o[k]=b2[k];
#pragma unroll
        for (int m=0;m<HH;m++){
            float hm=h1[m];
#pragma unroll
            for (int k=0;k<OUTC;k++) o[k] += hm * w2[m*OUTC+k];
        }

        float4* op = reinterpret_cast<float4*>(out + (((size_t)bnb*PP + i)*PP + j)*OUTC);
#pragma unroll
        for (int q=0;q<OUTC/4;q++)
            op[q]=make_float4(elu_f(o[4*q]),elu_f(o[4*q+1]),elu_f(o[4*q+2]),elu_f(o[4*q+3]));
    }
}

extern "C" void kernel_launch(void* const* d_in, const int* in_sizes, int n_in,
                              void* d_out, int out_size, void* d_ws, size_t ws_size,
                              hipStream_t stream) {
    const float* x    = (const float*)d_in[0];
    const float* msk  = (const float*)d_in[1];
    const float* nw0  = (const float*)d_in[2];
    const float* nb0  = (const float*)d_in[3];
    const float* nw1  = (const float*)d_in[4];
    const float* nb1  = (const float*)d_in[5];
    const float* nw2  = (const float*)d_in[6];
    const float* nb2  = (const float*)d_in[7];
    const float* pw0  = (const float*)d_in[8];
    const float* pb0  = (const float*)d_in[9];
    const float* pw1  = (const float*)d_in[10];
    const float* pb1  = (const float*)d_in[11];
    const float* pw2  = (const float*)d_in[12];
    const float* pb2  = (const float*)d_in[13];
    float* out = (float*)d_out;

    float* pa = (float*)d_ws;                       // 8192*32 floats = 1 MiB
    float* pb = pa + (size_t)NROWS*HH;              // +1 MiB

    node_kernel<<<NROWS/256, 256, 0, stream>>>(x, msk, nw0, nb0, nw1, nb1,
                                               nw2, nb2, pw0, pb0, pa, pb);
    pair_kernel<<<BB*NBB*(PP/ICHUNK), 128, 0, stream>>>(pa, pb, pw1, pb1,
                                                        pw2, pb2, out);
}